// Round 10
// baseline (131.926 us; speedup 1.0000x reference)
//
#include <hip/hip_runtime.h>
#include <hip/hip_bf16.h>

#define B_ 8
#define D_ 128
#define L_ 1024
#define KSZ 7
#define NH_ 8
#define DK_ 16

constexpr int BD = D_ * L_;
constexpr float LN_EPS = 1e-5f;
constexpr float INV_N = 1.0f / (float)BD;

typedef _Float16 half4 __attribute__((ext_vector_type(4)));
typedef _Float16 half8 __attribute__((ext_vector_type(8)));
typedef float f32x4 __attribute__((ext_vector_type(4)));

// ---------- 2-barrier block reduce: wave shuffle + tiny LDS hop ----------
template<int NS>
__device__ __forceinline__ void block_reduce_wave(float* s, float* redbuf, float* slot, int tid) {
    #pragma unroll
    for (int k = 0; k < NS; ++k) {
        float v = s[k];
        #pragma unroll
        for (int mk = 32; mk >= 1; mk >>= 1) v += __shfl_xor(v, mk, 64);
        s[k] = v;
    }
    int w = tid >> 6, lane = tid & 63;
    __syncthreads();
    if (lane == 0) {
        #pragma unroll
        for (int k = 0; k < NS; ++k) redbuf[w * NS + k] = s[k];
    }
    __syncthreads();
    if (tid == 0) {
        #pragma unroll
        for (int k = 0; k < NS; ++k)
            slot[k] = redbuf[k] + redbuf[NS + k] + redbuf[2 * NS + k] + redbuf[3 * NS + k];
    }
}

// ---------- wave-0 LN stats from 64 partial slots (8 floats each) ----------
template<int LNMODE>
__device__ __forceinline__ void ln_stats_wave0(
    const float* __restrict__ pin, const float* __restrict__ wmom,
    int b, float* stat4, int tid)
{
    if (tid < 64) {
        float s0=0,s1=0,s2=0,s3=0,s4=0,s5=0,w0=0,w1=0,w2=0,w3=0,w4=0;
        const float* p = pin + (b * 64 + tid) * 8;
        s0 = p[0]; s1 = p[1];
        if constexpr (LNMODE == 2) {
            s2 = p[2]; s3 = p[3]; s4 = p[4]; s5 = p[5];
            const float* q = wmom + tid * 8;
            w0 = q[0]; w1 = q[1]; w2 = q[2]; w3 = q[3]; w4 = q[4];
        }
        #pragma unroll
        for (int mk = 32; mk >= 1; mk >>= 1) {
            s0 += __shfl_xor(s0, mk, 64); s1 += __shfl_xor(s1, mk, 64);
            if constexpr (LNMODE == 2) {
                s2 += __shfl_xor(s2, mk, 64); s3 += __shfl_xor(s3, mk, 64);
                s4 += __shfl_xor(s4, mk, 64); s5 += __shfl_xor(s5, mk, 64);
                w0 += __shfl_xor(w0, mk, 64); w1 += __shfl_xor(w1, mk, 64);
                w2 += __shfl_xor(w2, mk, 64); w3 += __shfl_xor(w3, mk, 64);
                w4 += __shfl_xor(w4, mk, 64);
            }
        }
        if (tid == 0) {
            float m1 = s0 * INV_N;
            float r1 = rsqrtf(s1 * INV_N - m1 * m1 + LN_EPS);
            stat4[0] = m1; stat4[1] = r1;
            if constexpr (LNMODE == 2) {
                float Sy  = r1 * (s2 - m1 * w0) + w2;
                float Sy2 = r1 * r1 * (s4 - 2.f * m1 * s3 + m1 * m1 * w1)
                          + 2.f * r1 * (s5 - m1 * w4) + w3;
                float m2 = Sy * INV_N;
                float r2 = rsqrtf(Sy2 * INV_N - m2 * m2 + LN_EPS);
                stat4[2] = m2; stat4[3] = r2;
            }
        }
    }
    __syncthreads();
}

// ---------- pos-enc add + stats; b==8 row computes LN-weight moments ----------
__global__ __launch_bounds__(256) void k_addpos_wm(
    const float* __restrict__ x, const float* __restrict__ pos,
    const float* __restrict__ lnw, const float* __restrict__ lnb,
    float* __restrict__ out, float* __restrict__ part, float* __restrict__ wp)
{
    __shared__ float red[32];
    int b = blockIdx.y, blk = blockIdx.x, tid = threadIdx.x;
    if (b == 8) {
        int base = blk * 2048 + tid * 8;
        float s[5] = {0.f, 0.f, 0.f, 0.f, 0.f};
        #pragma unroll
        for (int q = 0; q < 2; ++q) {
            float4 wv = *(const float4*)(lnw + base + q * 4);
            float4 bv = *(const float4*)(lnb + base + q * 4);
            float wa[4] = {wv.x, wv.y, wv.z, wv.w};
            float ba[4] = {bv.x, bv.y, bv.z, bv.w};
            #pragma unroll
            for (int e = 0; e < 4; ++e) {
                float w = wa[e], bb = ba[e];
                s[0] += w; s[1] += w * w; s[2] += bb; s[3] += bb * bb; s[4] += w * bb;
            }
        }
        block_reduce_wave<5>(s, red, wp + blk * 8, tid);
        return;
    }
    int base = b * BD + blk * 2048;
    const float4* x4 = (const float4*)(x + base);
    const float4* p4 = (const float4*)(pos + blk * 2048);
    float4* o4 = (float4*)(out + base);
    float s[2] = {0.f, 0.f};
    #pragma unroll
    for (int j = 0; j < 2; ++j) {
        int idx = j * 256 + tid;
        float4 xv = x4[idx], pv = p4[idx];
        float4 r = {xv.x + pv.x, xv.y + pv.y, xv.z + pv.z, xv.w + pv.w};
        o4[idx] = r;
        s[0] += r.x + r.y + r.z + r.w;
        s[1] += r.x * r.x + r.y * r.y + r.z * r.z + r.w * r.w;
    }
    block_reduce_wave<2>(s, red, part + (b * 64 + blk) * 8, tid);
}

// ---------- fused conv block (tile 128o x 16l, grid (64, 8)) ----------
template<int LNMODE>
__global__ __launch_bounds__(256) void k_convblock(
    const float* __restrict__ src, const float* __restrict__ lnw, const float* __restrict__ lnb,
    const float* __restrict__ dwk, const float* __restrict__ pwk,
    const float* __restrict__ wmom, const float* __restrict__ pin,
    float* __restrict__ outbuf, float* __restrict__ pout)
{
    constexpr int XSTR = 136;
    constexpr int CSTR = 20;
    __shared__ _Float16 Xt[16 * XSTR];
    __shared__ float Ct[128 * CSTR];
    __shared__ float stat4[4];
    __shared__ float red[32];
    int lt = blockIdx.x, b = blockIdx.y;
    int tid = threadIdx.x;
    int l0 = lt * 16;

    ln_stats_wave0<LNMODE>(pin, wmom, b, stat4, tid);
    float m1 = stat4[0], r1 = stat4[1];
    float m2 = 0.f, r2 = 1.f;
    if constexpr (LNMODE == 2) { m2 = stat4[2]; r2 = stat4[3]; }

    {
        int c = tid >> 1, lh = tid & 1;
        int base = l0 + lh * 8;
        const float* srow = src + b * BD + c * L_;
        const float* wrow = lnw + c * L_;
        const float* brow = lnb + c * L_;
        float z[16];
        #pragma unroll
        for (int q = 0; q < 4; ++q) {
            int le = base - 4 + q * 4;
            if (le >= 0 && le <= L_ - 4) {
                float4 sv = *(const float4*)(srow + le);
                float4 wv = *(const float4*)(wrow + le);
                float4 bv = *(const float4*)(brow + le);
                float sa[4] = {sv.x, sv.y, sv.z, sv.w};
                float wa[4] = {wv.x, wv.y, wv.z, wv.w};
                float ba[4] = {bv.x, bv.y, bv.z, bv.w};
                #pragma unroll
                for (int e = 0; e < 4; ++e) {
                    float y = (sa[e] - m1) * r1 * wa[e] + ba[e];
                    if constexpr (LNMODE == 2) y = (y - m2) * r2 * wa[e] + ba[e];
                    z[q * 4 + e] = y;
                }
            } else {
                #pragma unroll
                for (int e = 0; e < 4; ++e) {
                    int l = le + e;
                    float zz = 0.f;
                    if (l >= 0 && l < L_) {
                        float y = (srow[l] - m1) * r1 * wrow[l] + brow[l];
                        if constexpr (LNMODE == 2) y = (y - m2) * r2 * wrow[l] + brow[l];
                        zz = y;
                    }
                    z[q * 4 + e] = zz;
                }
            }
        }
        float t0 = dwk[c*KSZ+0], t1 = dwk[c*KSZ+1], t2 = dwk[c*KSZ+2], t3 = dwk[c*KSZ+3],
              t4 = dwk[c*KSZ+4], t5 = dwk[c*KSZ+5], t6 = dwk[c*KSZ+6];
        #pragma unroll
        for (int j = 0; j < 8; ++j) {
            float o = t0*z[j+1] + t1*z[j+2] + t2*z[j+3] + t3*z[j+4]
                    + t4*z[j+5] + t5*z[j+6] + t6*z[j+7];
            Xt[(lh * 8 + j) * XSTR + c] = (_Float16)o;
        }
    }
    __syncthreads();

    int w = tid >> 6, lane = tid & 63, lg = lane >> 4, ln = lane & 15;
    int o0 = w * 32;
    const float* wrow0 = pwk + (o0 + ln) * D_;
    const float* wrow1 = pwk + (o0 + 16 + ln) * D_;
    f32x4 acc0 = {0.f, 0.f, 0.f, 0.f};
    f32x4 acc1 = {0.f, 0.f, 0.f, 0.f};
    #pragma unroll
    for (int kk = 0; kk < 8; ++kk) {
        float4 wv0 = *(const float4*)(wrow0 + kk * 16 + lg * 4);
        float4 wv1 = *(const float4*)(wrow1 + kk * 16 + lg * 4);
        half4 af0 = {(_Float16)wv0.x, (_Float16)wv0.y, (_Float16)wv0.z, (_Float16)wv0.w};
        half4 af1 = {(_Float16)wv1.x, (_Float16)wv1.y, (_Float16)wv1.z, (_Float16)wv1.w};
        half4 bf = *(const half4*)(&Xt[ln * XSTR + kk * 16 + lg * 4]);
        acc0 = __builtin_amdgcn_mfma_f32_16x16x16f16(af0, bf, acc0, 0, 0, 0);
        acc1 = __builtin_amdgcn_mfma_f32_16x16x16f16(af1, bf, acc1, 0, 0, 0);
    }

    #pragma unroll
    for (int om = 0; om < 2; ++om) {
        const f32x4& a = om ? acc1 : acc0;
        #pragma unroll
        for (int r = 0; r < 4; ++r)
            Ct[(o0 + om * 16 + lg * 4 + r) * CSTR + ln] = a[r];
    }
    __syncthreads();

    float s[6] = {0.f, 0.f, 0.f, 0.f, 0.f, 0.f};
    {
        int og = tid >> 1, hh = tid & 1;
        int lcol = l0 + hh * 8;
        int idx = b * BD + og * L_ + lcol;
        int widx = og * L_ + lcol;
        float4 c0 = *(const float4*)(&Ct[og * CSTR + hh * 8]);
        float4 c1 = *(const float4*)(&Ct[og * CSTR + hh * 8 + 4]);
        float4 rs0 = *(const float4*)(src + idx);
        float4 rs1 = *(const float4*)(src + idx + 4);
        float4 w0 = *(const float4*)(lnw + widx);
        float4 w1 = *(const float4*)(lnw + widx + 4);
        float4 b0 = *(const float4*)(lnb + widx);
        float4 b1 = *(const float4*)(lnb + widx + 4);
        float cv[8] = {c0.x, c0.y, c0.z, c0.w, c1.x, c1.y, c1.z, c1.w};
        float rv[8] = {rs0.x, rs0.y, rs0.z, rs0.w, rs1.x, rs1.y, rs1.z, rs1.w};
        float wv[8] = {w0.x, w0.y, w0.z, w0.w, w1.x, w1.y, w1.z, w1.w};
        float bv[8] = {b0.x, b0.y, b0.z, b0.w, b1.x, b1.y, b1.z, b1.w};
        float ov[8];
        #pragma unroll
        for (int e = 0; e < 8; ++e) {
            float v = fmaxf(cv[e], 0.f) + rv[e];
            ov[e] = v;
            float wvv = wv[e] * v;
            s[0] += v; s[1] += v * v; s[2] += wvv;
            s[3] += wv[e] * wvv; s[4] += wvv * wvv; s[5] += bv[e] * wvv;
        }
        *(float4*)(outbuf + idx)     = (float4){ov[0], ov[1], ov[2], ov[3]};
        *(float4*)(outbuf + idx + 4) = (float4){ov[4], ov[5], ov[6], ov[7]};
    }
    block_reduce_wave<6>(s, red, pout + (b * 64 + lt) * 8, tid);
}

// ---------- stage 32l x 128c tile with optional LN into Xt ----------
template<bool LNSTAGE, int XSTR>
__device__ __forceinline__ void stage_tile(
    const float* __restrict__ X, const float* __restrict__ lnw, const float* __restrict__ lnb,
    _Float16* Xt, int b, int l0, float m1, float r1, int tid)
{
    int c = tid >> 1, lh = tid & 1;
    int off = c * L_ + l0 + lh * 16;
    const float* xp = X + b * BD + off;
    const float* wp = lnw + off;
    const float* bp = lnb + off;
    #pragma unroll
    for (int q = 0; q < 4; ++q) {
        float4 v = *(const float4*)(xp + q * 4);
        if constexpr (LNSTAGE) {
            float4 wv = *(const float4*)(wp + q * 4);
            float4 bv = *(const float4*)(bp + q * 4);
            v.x = (v.x - m1) * r1 * wv.x + bv.x;
            v.y = (v.y - m1) * r1 * wv.y + bv.y;
            v.z = (v.z - m1) * r1 * wv.z + bv.z;
            v.w = (v.w - m1) * r1 * wv.w + bv.w;
        }
        int lb_ = lh * 16 + q * 4;
        Xt[(lb_ + 0) * XSTR + c] = (_Float16)v.x;
        Xt[(lb_ + 1) * XSTR + c] = (_Float16)v.y;
        Xt[(lb_ + 2) * XSTR + c] = (_Float16)v.z;
        Xt[(lb_ + 3) * XSTR + c] = (_Float16)v.w;
    }
}

// ---------- fused QKV: f16 fragment-ready outputs ----------
// Qt/Kt: [b][h][l][16] f16;  Vh: [b][h][v][l] f16.
// grid (32 lt, 2 rb, 8 b); rb covers heads rb*4..rb*4+3.
__global__ __launch_bounds__(256) void k_qkv(
    const float* __restrict__ Wq, const float* __restrict__ Wk, const float* __restrict__ Wv,
    const float* __restrict__ X, const float* __restrict__ lnw, const float* __restrict__ lnb,
    const float* __restrict__ pin,
    _Float16* __restrict__ Qt, _Float16* __restrict__ Kt, _Float16* __restrict__ Vh)
{
    constexpr int XSTR = 136;
    constexpr int CSTR = 36;
    __shared__ _Float16 Xt[32 * XSTR];
    __shared__ float Ct[64 * CSTR];
    __shared__ float stat4[4];
    int lt = blockIdx.x, rb = blockIdx.y, b = blockIdx.z;
    int tid = threadIdx.x;
    int l0 = lt * 32, r0 = rb * 64;

    ln_stats_wave0<1>(pin, nullptr, b, stat4, tid);
    stage_tile<true, XSTR>(X, lnw, lnb, Xt, b, l0, stat4[0], stat4[1], tid);
    __syncthreads();

    int w = tid >> 6, lane = tid & 63, lg = lane >> 4, ln = lane & 15;
    int o = r0 + w * 16 + ln;
    int woff = (o >> 4) * (B_ * DK_ * D_) + b * (DK_ * D_) + (o & 15) * D_;

    half4 bf[2][8];
    #pragma unroll
    for (int n = 0; n < 2; ++n)
        #pragma unroll
        for (int kk = 0; kk < 8; ++kk)
            bf[n][kk] = *(const half4*)(&Xt[(n * 16 + ln) * XSTR + kk * 16 + lg * 4]);

    const float* Wms[3] = {Wq, Wk, Wv};
    #pragma unroll
    for (int g = 0; g < 3; ++g) {
        const float* wrow = Wms[g] + woff;
        f32x4 acc0 = {0.f, 0.f, 0.f, 0.f};
        f32x4 acc1 = {0.f, 0.f, 0.f, 0.f};
        #pragma unroll
        for (int kk = 0; kk < 8; ++kk) {
            float4 wv = *(const float4*)(wrow + kk * 16 + lg * 4);
            half4 af = {(_Float16)wv.x, (_Float16)wv.y, (_Float16)wv.z, (_Float16)wv.w};
            acc0 = __builtin_amdgcn_mfma_f32_16x16x16f16(af, bf[0][kk], acc0, 0, 0, 0);
            acc1 = __builtin_amdgcn_mfma_f32_16x16x16f16(af, bf[1][kk], acc1, 0, 0, 0);
        }
        if (g) __syncthreads();
        #pragma unroll
        for (int n = 0; n < 2; ++n) {
            const f32x4& a = n ? acc1 : acc0;
            #pragma unroll
            for (int r = 0; r < 4; ++r)
                Ct[(w * 16 + lg * 4 + r) * CSTR + n * 16 + ln] = a[r];
        }
        __syncthreads();
        if (g < 2) {
            // Qt/Kt[b][h][l][16]: thread -> (hd, lrel, half)
            int hd = tid >> 6, lrel = (tid >> 1) & 31, hf = tid & 1;
            int h = rb * 4 + hd, l = l0 + lrel;
            half8 hv;
            #pragma unroll
            for (int k = 0; k < 8; ++k)
                hv[k] = (_Float16)Ct[(hd * 16 + hf * 8 + k) * CSTR + lrel];
            _Float16* dst = (g == 0 ? Qt : Kt);
            *(half8*)(dst + ((b * NH_ + h) * L_ + l) * 16 + hf * 8) = hv;
        } else {
            // Vh[b][h][v][l]: thread -> (row=o_local, q4)
            int row = tid >> 2, q4 = tid & 3;
            int h = rb * 4 + (row >> 4), v = row & 15;
            float4 c0 = *(const float4*)(&Ct[row * CSTR + q4 * 8]);
            float4 c1 = *(const float4*)(&Ct[row * CSTR + q4 * 8 + 4]);
            half8 hv = {(_Float16)c0.x, (_Float16)c0.y, (_Float16)c0.z, (_Float16)c0.w,
                        (_Float16)c1.x, (_Float16)c1.y, (_Float16)c1.z, (_Float16)c1.w};
            *(half8*)(Vh + ((b * NH_ + h) * DK_ + v) * L_ + l0 + q4 * 8) = hv;
        }
    }
}

// ---------- LDS-free MFMA attention (no-max softmax) ----------
// grid (16 mt, 8 h, 8 b), block 256 (4 waves x 16 m). Output H16[b][l][c] f16.
__global__ __launch_bounds__(256) void k_attn_mfma(
    const _Float16* __restrict__ Qt, const _Float16* __restrict__ Kt,
    const _Float16* __restrict__ Vh, _Float16* __restrict__ H16)
{
    __shared__ _Float16 Om[64 * 16];
    int mt = blockIdx.x, h = blockIdx.y, b = blockIdx.z;
    int tid = threadIdx.x;
    int w = tid >> 6, lane = tid & 63, lg = lane >> 4, ln = lane & 15;
    int m = mt * 64 + w * 16 + ln;
    const _Float16* Qh = Qt + (b * NH_ + h) * L_ * 16;
    const _Float16* Kh = Kt + (b * NH_ + h) * L_ * 16;
    const _Float16* Vp = Vh + (b * NH_ + h) * DK_ * L_;

    half4 kraw = *(const half4*)(Kh + m * 16 + lg * 4);
    half4 kfrag;
    #pragma unroll
    for (int j = 0; j < 4; ++j) kfrag[j] = kraw[j] * (_Float16)0.25f;

    f32x4 accf[4];
    #pragma unroll
    for (int f = 0; f < 4; ++f) accf[f] = (f32x4){0.f, 0.f, 0.f, 0.f};
    float run_sm = 0.f;

    for (int lt = 0; lt < 16; ++lt) {
        int l0 = lt * 64;
        f32x4 s[4];
        #pragma unroll
        for (int f = 0; f < 4; ++f) {
            half4 qf = *(const half4*)(Qh + (l0 + f * 16 + ln) * 16 + lg * 4);
            f32x4 z = {0.f, 0.f, 0.f, 0.f};
            s[f] = __builtin_amdgcn_mfma_f32_16x16x16f16(qf, kfrag, z, 0, 0, 0);
        }
        float ts = 0.f;
        half4 pf[4];
        #pragma unroll
        for (int f = 0; f < 4; ++f) {
            float p0 = __expf(s[f][0]);
            float p1 = __expf(s[f][1]);
            float p2 = __expf(s[f][2]);
            float p3 = __expf(s[f][3]);
            ts += (p0 + p1) + (p2 + p3);
            pf[f][0] = (_Float16)p0; pf[f][1] = (_Float16)p1;
            pf[f][2] = (_Float16)p2; pf[f][3] = (_Float16)p3;
        }
        ts += __shfl_xor(ts, 16, 64);
        ts += __shfl_xor(ts, 32, 64);
        run_sm += ts;
        #pragma unroll
        for (int f = 0; f < 4; ++f) {
            half4 vf = *(const half4*)(Vp + ln * L_ + l0 + f * 16 + lg * 4);
            accf[f] = __builtin_amdgcn_mfma_f32_16x16x16f16(vf, pf[f], accf[f], 0, 0, 0);
        }
    }

    float inv = 1.f / run_sm;
    #pragma unroll
    for (int r = 0; r < 4; ++r) {
        float a = (accf[0][r] + accf[1][r]) + (accf[2][r] + accf[3][r]);
        Om[(w * 16 + ln) * 16 + lg * 4 + r] = (_Float16)(a * inv);
    }
    __syncthreads();
    if (tid < 128) {
        int ml = tid >> 1, hf = tid & 1;
        half8 hv = *(const half8*)(&Om[ml * 16 + hf * 8]);
        *(half8*)(H16 + (b * L_ + mt * 64 + ml) * 128 + h * 16 + hf * 8) = hv;
    }
}

// ---------- Wo matmul: B-frags direct from H16 (no staging) ----------
// grid (32 lt, 2 rb, 8 b); d = Wo @ heads + res; plain stats out.
__global__ __launch_bounds__(256) void k_matmul_h16(
    const float* __restrict__ Wm, const _Float16* __restrict__ H16,
    const float* __restrict__ res, float* __restrict__ out, float* __restrict__ part)
{
    constexpr int CSTR = 36;
    __shared__ float Ct[64 * CSTR];
    __shared__ float red[32];
    int lt = blockIdx.x, rb = blockIdx.y, b = blockIdx.z;
    int tid = threadIdx.x;
    int l0 = lt * 32, r0 = rb * 64;

    int w = tid >> 6, lane = tid & 63, lg = lane >> 4, ln = lane & 15;
    int o = r0 + w * 16 + ln;
    const float* wrow = Wm + b * D_ * D_ + o * D_;
    const _Float16* Hb = H16 + (size_t)b * L_ * 128;

    f32x4 acc0 = {0.f, 0.f, 0.f, 0.f};
    f32x4 acc1 = {0.f, 0.f, 0.f, 0.f};
    #pragma unroll
    for (int kk = 0; kk < 8; ++kk) {
        float4 wv = *(const float4*)(wrow + kk * 16 + lg * 4);
        half4 af = {(_Float16)wv.x, (_Float16)wv.y, (_Float16)wv.z, (_Float16)wv.w};
        half4 b0 = *(const half4*)(Hb + (l0 + ln) * 128 + kk * 16 + lg * 4);
        half4 b1 = *(const half4*)(Hb + (l0 + 16 + ln) * 128 + kk * 16 + lg * 4);
        acc0 = __builtin_amdgcn_mfma_f32_16x16x16f16(af, b0, acc0, 0, 0, 0);
        acc1 = __builtin_amdgcn_mfma_f32_16x16x16f16(af, b1, acc1, 0, 0, 0);
    }

    #pragma unroll
    for (int n = 0; n < 2; ++n) {
        const f32x4& a = n ? acc1 : acc0;
        #pragma unroll
        for (int r = 0; r < 4; ++r)
            Ct[(w * 16 + lg * 4 + r) * CSTR + n * 16 + ln] = a[r];
    }
    __syncthreads();

    float s[2] = {0.f, 0.f};
    {
        int row = tid >> 2, q4 = tid & 3;
        int og = r0 + row, lcol = l0 + q4 * 8;
        int idx = b * BD + og * L_ + lcol;
        float4 c0 = *(const float4*)(&Ct[row * CSTR + q4 * 8]);
        float4 c1 = *(const float4*)(&Ct[row * CSTR + q4 * 8 + 4]);
        float4 r0v = *(const float4*)(res + idx);
        float4 r1v = *(const float4*)(res + idx + 4);
        float cv[8] = {c0.x, c0.y, c0.z, c0.w, c1.x, c1.y, c1.z, c1.w};
        float rv[8] = {r0v.x, r0v.y, r0v.z, r0v.w, r1v.x, r1v.y, r1v.z, r1v.w};
        float ov[8];
        #pragma unroll
        for (int e = 0; e < 8; ++e) {
            float v = cv[e] + rv[e];
            ov[e] = v;
            s[0] += v; s[1] += v * v;
        }
        *(float4*)(out + idx)     = (float4){ov[0], ov[1], ov[2], ov[3]};
        *(float4*)(out + idx + 4) = (float4){ov[4], ov[5], ov[6], ov[7]};
    }
    block_reduce_wave<2>(s, red, part + (b * 64 + rb * 32 + lt) * 8, tid);
}

// ---------- generic MFMA matmul (W[b,o,c]) with LN staging ----------
template<bool RELU, bool ADDRES, bool STATS, bool LNSTAGE>
__global__ __launch_bounds__(256) void k_matmul_mfma(
    const float* __restrict__ Wm, const float* __restrict__ X,
    const float* __restrict__ lnw, const float* __restrict__ lnb,
    const float* __restrict__ pin,
    const float* __restrict__ res, float* __restrict__ out, float* __restrict__ part)
{
    constexpr int XSTR = 136;
    constexpr int CSTR = 36;
    __shared__ _Float16 Xt[32 * XSTR];
    __shared__ float Ct[64 * CSTR];
    __shared__ float stat4[4];
    __shared__ float red[32];
    int lt = blockIdx.x, rb = blockIdx.y, b = blockIdx.z;
    int tid = threadIdx.x;
    int l0 = lt * 32, r0 = rb * 64;

    if constexpr (LNSTAGE) ln_stats_wave0<1>(pin, nullptr, b, stat4, tid);
    float m1 = LNSTAGE ? stat4[0] : 0.f, r1 = LNSTAGE ? stat4[1] : 1.f;
    stage_tile<LNSTAGE, XSTR>(X, lnw, lnb, Xt, b, l0, m1, r1, tid);
    __syncthreads();

    int w = tid >> 6, lane = tid & 63, lg = lane >> 4, ln = lane & 15;
    int o = r0 + w * 16 + ln;
    const float* wrow = Wm + b * D_ * D_ + o * D_;

    f32x4 acc0 = {0.f, 0.f, 0.f, 0.f};
    f32x4 acc1 = {0.f, 0.f, 0.f, 0.f};
    #pragma unroll
    for (int kk = 0; kk < 8; ++kk) {
        float4 wv = *(const float4*)(wrow + kk * 16 + lg * 4);
        half4 af = {(_Float16)wv.x, (_Float16)wv.y, (_Float16)wv.z, (_Float16)wv.w};
        half4 b0 = *(const half4*)(&Xt[ln * XSTR + kk * 16 + lg * 4]);
        half4 b1 = *(const half4*)(&Xt[(16 + ln) * XSTR + kk * 16 + lg * 4]);
        acc0 = __builtin_amdgcn_mfma_f32_16x16x16f16(af, b0, acc0, 0, 0, 0);
        acc1 = __builtin_amdgcn_mfma_f32_16x16x16f16(af, b1, acc1, 0, 0, 0);
    }

    #pragma unroll
    for (int n = 0; n < 2; ++n) {
        const f32x4& a = n ? acc1 : acc0;
        #pragma unroll
        for (int r = 0; r < 4; ++r)
            Ct[(w * 16 + lg * 4 + r) * CSTR + n * 16 + ln] = a[r];
    }
    __syncthreads();

    float s[2] = {0.f, 0.f};
    {
        int row = tid >> 2, q4 = tid & 3;
        int og = r0 + row, lcol = l0 + q4 * 8;
        int idx = b * BD + og * L_ + lcol;
        float4 c0 = *(const float4*)(&Ct[row * CSTR + q4 * 8]);
        float4 c1 = *(const float4*)(&Ct[row * CSTR + q4 * 8 + 4]);
        float cv[8] = {c0.x, c0.y, c0.z, c0.w, c1.x, c1.y, c1.z, c1.w};
        float rv[8] = {0.f, 0.f, 0.f, 0.f, 0.f, 0.f, 0.f, 0.f};
        if constexpr (ADDRES) {
            float4 r0v = *(const float4*)(res + idx);
            float4 r1v = *(const float4*)(res + idx + 4);
            rv[0]=r0v.x; rv[1]=r0v.y; rv[2]=r0v.z; rv[3]=r0v.w;
            rv[4]=r1v.x; rv[5]=r1v.y; rv[6]=r1v.z; rv[7]=r1v.w;
        }
        float ov[8];
        #pragma unroll
        for (int e = 0; e < 8; ++e) {
            float v = cv[e];
            if constexpr (RELU) v = fmaxf(v, 0.f);
            v += rv[e];
            ov[e] = v;
            if constexpr (STATS) { s[0] += v; s[1] += v * v; }
        }
        *(float4*)(out + idx)     = (float4){ov[0], ov[1], ov[2], ov[3]};
        *(float4*)(out + idx + 4) = (float4){ov[4], ov[5], ov[6], ov[7]};
    }
    if constexpr (STATS) block_reduce_wave<2>(s, red, part + (b * 64 + rb * 32 + lt) * 8, tid);
}

// ---------- launch ----------

extern "C" void kernel_launch(void* const* d_in, const int* in_sizes, int n_in,
                              void* d_out, int out_size, void* d_ws, size_t ws_size,
                              hipStream_t stream)
{
    const float* x   = (const float*)d_in[0];
    const float* pos = (const float*)d_in[1];
    const float* lnw = (const float*)d_in[2];
    const float* lnb = (const float*)d_in[3];
    const float* dw  = (const float*)d_in[4];
    const float* pw  = (const float*)d_in[5];
    const float* Wq  = (const float*)d_in[6];
    const float* Wk  = (const float*)d_in[7];
    const float* Wv  = (const float*)d_in[8];
    const float* Wo  = (const float*)d_in[9];
    const float* Wf  = (const float*)d_in[10];
    float* out = (float*)d_out;

    float* ws = (float*)d_ws;
    float* WP = ws;                         // 64*8
    float* P0 = ws + 512;                   // each 8*64*8 = 4096 floats
    float* P1 = P0 + 4096;
    float* P2 = P1 + 4096;
    float* P3 = P2 + 4096;
    float* P4 = P3 + 4096;
    float* P5 = P4 + 4096;
    float* bufA = ws + 32768;
    float* bufB = bufA + (size_t)B_ * BD;
    float* bufC = bufB + (size_t)B_ * BD;   // d (Wo out)
    _Float16* Qt  = (_Float16*)(bufC + (size_t)B_ * BD);
    _Float16* Kt  = Qt + (size_t)B_ * NH_ * L_ * 16;
    _Float16* Vh  = Kt + (size_t)B_ * NH_ * L_ * 16;
    _Float16* H16 = Vh + (size_t)B_ * NH_ * DK_ * L_;

    dim3 cb(64, 8);
    dim3 mb(32, 2, 8);

    k_addpos_wm<<<dim3(64, 9), 256, 0, stream>>>(x, pos, lnw, lnb, bufA, P0, WP);

    k_convblock<1><<<cb, 256, 0, stream>>>(bufA, lnw, lnb, dw + 0*D_*KSZ, pw + 0*D_*D_, WP, P0, bufB, P1);
    k_convblock<2><<<cb, 256, 0, stream>>>(bufB, lnw, lnb, dw + 1*D_*KSZ, pw + 1*D_*D_, WP, P1, bufA, P2);
    k_convblock<2><<<cb, 256, 0, stream>>>(bufA, lnw, lnb, dw + 2*D_*KSZ, pw + 2*D_*D_, WP, P2, bufB, P3);
    k_convblock<2><<<cb, 256, 0, stream>>>(bufB, lnw, lnb, dw + 3*D_*KSZ, pw + 3*D_*D_, WP, P3, bufA, P4);

    k_qkv<<<mb, 256, 0, stream>>>(Wq, Wk, Wv, bufA, lnw, lnb, P4, Qt, Kt, Vh);

    k_attn_mfma<<<dim3(16, NH_, B_), 256, 0, stream>>>(Qt, Kt, Vh, H16);

    k_matmul_h16<<<mb, 256, 0, stream>>>(Wo, H16, bufA, bufC, P5);
    k_matmul_mfma<true, true, false, true><<<mb, 256, 0, stream>>>(Wf, bufC, lnw, lnb, P5, bufC, out, nullptr);
}

// Round 11
// 109.219 us; speedup vs baseline: 1.2079x; 1.2079x over previous
//
#include <hip/hip_runtime.h>
#include <hip/hip_bf16.h>

#define B_ 8
#define D_ 128
#define L_ 1024
#define KSZ 7
#define NH_ 8
#define DK_ 16

constexpr int BD = D_ * L_;
constexpr float LN_EPS = 1e-5f;
constexpr float INV_N = 1.0f / (float)BD;

typedef _Float16 half4 __attribute__((ext_vector_type(4)));
typedef _Float16 half8 __attribute__((ext_vector_type(8)));
typedef float f32x4 __attribute__((ext_vector_type(4)));

// ---------- 2-barrier block reduce: wave shuffle + tiny LDS hop ----------
template<int NS>
__device__ __forceinline__ void block_reduce_wave(float* s, float* redbuf, float* slot, int tid) {
    #pragma unroll
    for (int k = 0; k < NS; ++k) {
        float v = s[k];
        #pragma unroll
        for (int mk = 32; mk >= 1; mk >>= 1) v += __shfl_xor(v, mk, 64);
        s[k] = v;
    }
    int w = tid >> 6, lane = tid & 63;
    __syncthreads();
    if (lane == 0) {
        #pragma unroll
        for (int k = 0; k < NS; ++k) redbuf[w * NS + k] = s[k];
    }
    __syncthreads();
    if (tid == 0) {
        #pragma unroll
        for (int k = 0; k < NS; ++k)
            slot[k] = redbuf[k] + redbuf[NS + k] + redbuf[2 * NS + k] + redbuf[3 * NS + k];
    }
}

// ---------- wave-0 LN stats from 64 partial slots (8 floats each) ----------
template<int LNMODE>
__device__ __forceinline__ void ln_stats_wave0(
    const float* __restrict__ pin, const float* __restrict__ wmom,
    int b, float* stat4, int tid)
{
    if (tid < 64) {
        float s0=0,s1=0,s2=0,s3=0,s4=0,s5=0,w0=0,w1=0,w2=0,w3=0,w4=0;
        const float* p = pin + (b * 64 + tid) * 8;
        s0 = p[0]; s1 = p[1];
        if constexpr (LNMODE == 2) {
            s2 = p[2]; s3 = p[3]; s4 = p[4]; s5 = p[5];
            const float* q = wmom + tid * 8;
            w0 = q[0]; w1 = q[1]; w2 = q[2]; w3 = q[3]; w4 = q[4];
        }
        #pragma unroll
        for (int mk = 32; mk >= 1; mk >>= 1) {
            s0 += __shfl_xor(s0, mk, 64); s1 += __shfl_xor(s1, mk, 64);
            if constexpr (LNMODE == 2) {
                s2 += __shfl_xor(s2, mk, 64); s3 += __shfl_xor(s3, mk, 64);
                s4 += __shfl_xor(s4, mk, 64); s5 += __shfl_xor(s5, mk, 64);
                w0 += __shfl_xor(w0, mk, 64); w1 += __shfl_xor(w1, mk, 64);
                w2 += __shfl_xor(w2, mk, 64); w3 += __shfl_xor(w3, mk, 64);
                w4 += __shfl_xor(w4, mk, 64);
            }
        }
        if (tid == 0) {
            float m1 = s0 * INV_N;
            float r1 = rsqrtf(s1 * INV_N - m1 * m1 + LN_EPS);
            stat4[0] = m1; stat4[1] = r1;
            if constexpr (LNMODE == 2) {
                float Sy  = r1 * (s2 - m1 * w0) + w2;
                float Sy2 = r1 * r1 * (s4 - 2.f * m1 * s3 + m1 * m1 * w1)
                          + 2.f * r1 * (s5 - m1 * w4) + w3;
                float m2 = Sy * INV_N;
                float r2 = rsqrtf(Sy2 * INV_N - m2 * m2 + LN_EPS);
                stat4[2] = m2; stat4[3] = r2;
            }
        }
    }
    __syncthreads();
}

// ---------- pos-enc add + stats; b==8 row computes LN-weight moments ----------
__global__ __launch_bounds__(256) void k_addpos_wm(
    const float* __restrict__ x, const float* __restrict__ pos,
    const float* __restrict__ lnw, const float* __restrict__ lnb,
    float* __restrict__ out, float* __restrict__ part, float* __restrict__ wp)
{
    __shared__ float red[32];
    int b = blockIdx.y, blk = blockIdx.x, tid = threadIdx.x;
    if (b == 8) {
        int base = blk * 2048 + tid * 8;
        float s[5] = {0.f, 0.f, 0.f, 0.f, 0.f};
        #pragma unroll
        for (int q = 0; q < 2; ++q) {
            float4 wv = *(const float4*)(lnw + base + q * 4);
            float4 bv = *(const float4*)(lnb + base + q * 4);
            float wa[4] = {wv.x, wv.y, wv.z, wv.w};
            float ba[4] = {bv.x, bv.y, bv.z, bv.w};
            #pragma unroll
            for (int e = 0; e < 4; ++e) {
                float w = wa[e], bb = ba[e];
                s[0] += w; s[1] += w * w; s[2] += bb; s[3] += bb * bb; s[4] += w * bb;
            }
        }
        block_reduce_wave<5>(s, red, wp + blk * 8, tid);
        return;
    }
    int base = b * BD + blk * 2048;
    const float4* x4 = (const float4*)(x + base);
    const float4* p4 = (const float4*)(pos + blk * 2048);
    float4* o4 = (float4*)(out + base);
    float s[2] = {0.f, 0.f};
    #pragma unroll
    for (int j = 0; j < 2; ++j) {
        int idx = j * 256 + tid;
        float4 xv = x4[idx], pv = p4[idx];
        float4 r = {xv.x + pv.x, xv.y + pv.y, xv.z + pv.z, xv.w + pv.w};
        o4[idx] = r;
        s[0] += r.x + r.y + r.z + r.w;
        s[1] += r.x * r.x + r.y * r.y + r.z * r.z + r.w * r.w;
    }
    block_reduce_wave<2>(s, red, part + (b * 64 + blk) * 8, tid);
}

// ---------- fused conv block (tile 128o x 16l, grid (64, 8)) ----------
template<int LNMODE>
__global__ __launch_bounds__(256) void k_convblock(
    const float* __restrict__ src, const float* __restrict__ lnw, const float* __restrict__ lnb,
    const float* __restrict__ dwk, const float* __restrict__ pwk,
    const float* __restrict__ wmom, const float* __restrict__ pin,
    float* __restrict__ outbuf, float* __restrict__ pout)
{
    constexpr int XSTR = 136;
    constexpr int CSTR = 20;
    __shared__ _Float16 Xt[16 * XSTR];
    __shared__ float Ct[128 * CSTR];
    __shared__ float stat4[4];
    __shared__ float red[32];
    int lt = blockIdx.x, b = blockIdx.y;
    int tid = threadIdx.x;
    int l0 = lt * 16;

    ln_stats_wave0<LNMODE>(pin, wmom, b, stat4, tid);
    float m1 = stat4[0], r1 = stat4[1];
    float m2 = 0.f, r2 = 1.f;
    if constexpr (LNMODE == 2) { m2 = stat4[2]; r2 = stat4[3]; }

    {
        int c = tid >> 1, lh = tid & 1;
        int base = l0 + lh * 8;
        const float* srow = src + b * BD + c * L_;
        const float* wrow = lnw + c * L_;
        const float* brow = lnb + c * L_;
        float z[16];
        #pragma unroll
        for (int q = 0; q < 4; ++q) {
            int le = base - 4 + q * 4;
            if (le >= 0 && le <= L_ - 4) {
                float4 sv = *(const float4*)(srow + le);
                float4 wv = *(const float4*)(wrow + le);
                float4 bv = *(const float4*)(brow + le);
                float sa[4] = {sv.x, sv.y, sv.z, sv.w};
                float wa[4] = {wv.x, wv.y, wv.z, wv.w};
                float ba[4] = {bv.x, bv.y, bv.z, bv.w};
                #pragma unroll
                for (int e = 0; e < 4; ++e) {
                    float y = (sa[e] - m1) * r1 * wa[e] + ba[e];
                    if constexpr (LNMODE == 2) y = (y - m2) * r2 * wa[e] + ba[e];
                    z[q * 4 + e] = y;
                }
            } else {
                #pragma unroll
                for (int e = 0; e < 4; ++e) {
                    int l = le + e;
                    float zz = 0.f;
                    if (l >= 0 && l < L_) {
                        float y = (srow[l] - m1) * r1 * wrow[l] + brow[l];
                        if constexpr (LNMODE == 2) y = (y - m2) * r2 * wrow[l] + brow[l];
                        zz = y;
                    }
                    z[q * 4 + e] = zz;
                }
            }
        }
        float t0 = dwk[c*KSZ+0], t1 = dwk[c*KSZ+1], t2 = dwk[c*KSZ+2], t3 = dwk[c*KSZ+3],
              t4 = dwk[c*KSZ+4], t5 = dwk[c*KSZ+5], t6 = dwk[c*KSZ+6];
        #pragma unroll
        for (int j = 0; j < 8; ++j) {
            float o = t0*z[j+1] + t1*z[j+2] + t2*z[j+3] + t3*z[j+4]
                    + t4*z[j+5] + t5*z[j+6] + t6*z[j+7];
            Xt[(lh * 8 + j) * XSTR + c] = (_Float16)o;
        }
    }
    __syncthreads();

    int w = tid >> 6, lane = tid & 63, lg = lane >> 4, ln = lane & 15;
    int o0 = w * 32;
    const float* wrow0 = pwk + (o0 + ln) * D_;
    const float* wrow1 = pwk + (o0 + 16 + ln) * D_;
    f32x4 acc0 = {0.f, 0.f, 0.f, 0.f};
    f32x4 acc1 = {0.f, 0.f, 0.f, 0.f};
    #pragma unroll
    for (int kk = 0; kk < 8; ++kk) {
        float4 wv0 = *(const float4*)(wrow0 + kk * 16 + lg * 4);
        float4 wv1 = *(const float4*)(wrow1 + kk * 16 + lg * 4);
        half4 af0 = {(_Float16)wv0.x, (_Float16)wv0.y, (_Float16)wv0.z, (_Float16)wv0.w};
        half4 af1 = {(_Float16)wv1.x, (_Float16)wv1.y, (_Float16)wv1.z, (_Float16)wv1.w};
        half4 bf = *(const half4*)(&Xt[ln * XSTR + kk * 16 + lg * 4]);
        acc0 = __builtin_amdgcn_mfma_f32_16x16x16f16(af0, bf, acc0, 0, 0, 0);
        acc1 = __builtin_amdgcn_mfma_f32_16x16x16f16(af1, bf, acc1, 0, 0, 0);
    }

    #pragma unroll
    for (int om = 0; om < 2; ++om) {
        const f32x4& a = om ? acc1 : acc0;
        #pragma unroll
        for (int r = 0; r < 4; ++r)
            Ct[(o0 + om * 16 + lg * 4 + r) * CSTR + ln] = a[r];
    }
    __syncthreads();

    float s[6] = {0.f, 0.f, 0.f, 0.f, 0.f, 0.f};
    {
        int og = tid >> 1, hh = tid & 1;
        int lcol = l0 + hh * 8;
        int idx = b * BD + og * L_ + lcol;
        int widx = og * L_ + lcol;
        float4 c0 = *(const float4*)(&Ct[og * CSTR + hh * 8]);
        float4 c1 = *(const float4*)(&Ct[og * CSTR + hh * 8 + 4]);
        float4 rs0 = *(const float4*)(src + idx);
        float4 rs1 = *(const float4*)(src + idx + 4);
        float4 w0 = *(const float4*)(lnw + widx);
        float4 w1 = *(const float4*)(lnw + widx + 4);
        float4 b0 = *(const float4*)(lnb + widx);
        float4 b1 = *(const float4*)(lnb + widx + 4);
        float cv[8] = {c0.x, c0.y, c0.z, c0.w, c1.x, c1.y, c1.z, c1.w};
        float rv[8] = {rs0.x, rs0.y, rs0.z, rs0.w, rs1.x, rs1.y, rs1.z, rs1.w};
        float wv[8] = {w0.x, w0.y, w0.z, w0.w, w1.x, w1.y, w1.z, w1.w};
        float bv[8] = {b0.x, b0.y, b0.z, b0.w, b1.x, b1.y, b1.z, b1.w};
        float ov[8];
        #pragma unroll
        for (int e = 0; e < 8; ++e) {
            float v = fmaxf(cv[e], 0.f) + rv[e];
            ov[e] = v;
            float wvv = wv[e] * v;
            s[0] += v; s[1] += v * v; s[2] += wvv;
            s[3] += wv[e] * wvv; s[4] += wvv * wvv; s[5] += bv[e] * wvv;
        }
        *(float4*)(outbuf + idx)     = (float4){ov[0], ov[1], ov[2], ov[3]};
        *(float4*)(outbuf + idx + 4) = (float4){ov[4], ov[5], ov[6], ov[7]};
    }
    block_reduce_wave<6>(s, red, pout + (b * 64 + lt) * 8, tid);
}

// ---------- stage 32l x 128c tile with optional LN into Xt ----------
template<bool LNSTAGE, int XSTR>
__device__ __forceinline__ void stage_tile(
    const float* __restrict__ X, const float* __restrict__ lnw, const float* __restrict__ lnb,
    _Float16* Xt, int b, int l0, float m1, float r1, int tid)
{
    int c = tid >> 1, lh = tid & 1;
    int off = c * L_ + l0 + lh * 16;
    const float* xp = X + b * BD + off;
    const float* wp = lnw + off;
    const float* bp = lnb + off;
    #pragma unroll
    for (int q = 0; q < 4; ++q) {
        float4 v = *(const float4*)(xp + q * 4);
        if constexpr (LNSTAGE) {
            float4 wv = *(const float4*)(wp + q * 4);
            float4 bv = *(const float4*)(bp + q * 4);
            v.x = (v.x - m1) * r1 * wv.x + bv.x;
            v.y = (v.y - m1) * r1 * wv.y + bv.y;
            v.z = (v.z - m1) * r1 * wv.z + bv.z;
            v.w = (v.w - m1) * r1 * wv.w + bv.w;
        }
        int lb_ = lh * 16 + q * 4;
        Xt[(lb_ + 0) * XSTR + c] = (_Float16)v.x;
        Xt[(lb_ + 1) * XSTR + c] = (_Float16)v.y;
        Xt[(lb_ + 2) * XSTR + c] = (_Float16)v.z;
        Xt[(lb_ + 3) * XSTR + c] = (_Float16)v.w;
    }
}

// ---------- fused QKV: f16 fragment-ready outputs ----------
__global__ __launch_bounds__(256) void k_qkv(
    const float* __restrict__ Wq, const float* __restrict__ Wk, const float* __restrict__ Wv,
    const float* __restrict__ X, const float* __restrict__ lnw, const float* __restrict__ lnb,
    const float* __restrict__ pin,
    _Float16* __restrict__ Qt, _Float16* __restrict__ Kt, _Float16* __restrict__ Vh)
{
    constexpr int XSTR = 136;
    constexpr int CSTR = 36;
    __shared__ _Float16 Xt[32 * XSTR];
    __shared__ float Ct[64 * CSTR];
    __shared__ float stat4[4];
    int lt = blockIdx.x, rb = blockIdx.y, b = blockIdx.z;
    int tid = threadIdx.x;
    int l0 = lt * 32, r0 = rb * 64;

    ln_stats_wave0<1>(pin, nullptr, b, stat4, tid);
    stage_tile<true, XSTR>(X, lnw, lnb, Xt, b, l0, stat4[0], stat4[1], tid);
    __syncthreads();

    int w = tid >> 6, lane = tid & 63, lg = lane >> 4, ln = lane & 15;
    int o = r0 + w * 16 + ln;
    int woff = (o >> 4) * (B_ * DK_ * D_) + b * (DK_ * D_) + (o & 15) * D_;

    half4 bf[2][8];
    #pragma unroll
    for (int n = 0; n < 2; ++n)
        #pragma unroll
        for (int kk = 0; kk < 8; ++kk)
            bf[n][kk] = *(const half4*)(&Xt[(n * 16 + ln) * XSTR + kk * 16 + lg * 4]);

    const float* Wms[3] = {Wq, Wk, Wv};
    #pragma unroll
    for (int g = 0; g < 3; ++g) {
        const float* wrow = Wms[g] + woff;
        f32x4 acc0 = {0.f, 0.f, 0.f, 0.f};
        f32x4 acc1 = {0.f, 0.f, 0.f, 0.f};
        #pragma unroll
        for (int kk = 0; kk < 8; ++kk) {
            float4 wv = *(const float4*)(wrow + kk * 16 + lg * 4);
            half4 af = {(_Float16)wv.x, (_Float16)wv.y, (_Float16)wv.z, (_Float16)wv.w};
            acc0 = __builtin_amdgcn_mfma_f32_16x16x16f16(af, bf[0][kk], acc0, 0, 0, 0);
            acc1 = __builtin_amdgcn_mfma_f32_16x16x16f16(af, bf[1][kk], acc1, 0, 0, 0);
        }
        if (g) __syncthreads();
        #pragma unroll
        for (int n = 0; n < 2; ++n) {
            const f32x4& a = n ? acc1 : acc0;
            #pragma unroll
            for (int r = 0; r < 4; ++r)
                Ct[(w * 16 + lg * 4 + r) * CSTR + n * 16 + ln] = a[r];
        }
        __syncthreads();
        if (g < 2) {
            int hd = tid >> 6, lrel = (tid >> 1) & 31, hf = tid & 1;
            int h = rb * 4 + hd, l = l0 + lrel;
            half8 hv;
            #pragma unroll
            for (int k = 0; k < 8; ++k)
                hv[k] = (_Float16)Ct[(hd * 16 + hf * 8 + k) * CSTR + lrel];
            _Float16* dst = (g == 0 ? Qt : Kt);
            *(half8*)(dst + ((b * NH_ + h) * L_ + l) * 16 + hf * 8) = hv;
        } else {
            int row = tid >> 2, q4 = tid & 3;
            int h = rb * 4 + (row >> 4), v = row & 15;
            float4 c0 = *(const float4*)(&Ct[row * CSTR + q4 * 8]);
            float4 c1 = *(const float4*)(&Ct[row * CSTR + q4 * 8 + 4]);
            half8 hv = {(_Float16)c0.x, (_Float16)c0.y, (_Float16)c0.z, (_Float16)c0.w,
                        (_Float16)c1.x, (_Float16)c1.y, (_Float16)c1.z, (_Float16)c1.w};
            *(half8*)(Vh + ((b * NH_ + h) * DK_ + v) * L_ + l0 + q4 * 8) = hv;
        }
    }
}

// ---------- MFMA attention: Q/K direct (coalesced), V via single-barrier dbuf LDS ----------
// grid (16 mt, 8 h, 8 b), block 256. Output H16[b][l][c] f16.
__global__ __launch_bounds__(256) void k_attn_mfma(
    const _Float16* __restrict__ Qt, const _Float16* __restrict__ Kt,
    const _Float16* __restrict__ Vh, _Float16* __restrict__ H16)
{
    constexpr int VSTR = 72;
    __shared__ _Float16 Vs[2][16 * VSTR];
    __shared__ _Float16 Om[64 * 16];
    int mt = blockIdx.x, h = blockIdx.y, b = blockIdx.z;
    int tid = threadIdx.x;
    int w = tid >> 6, lane = tid & 63, lg = lane >> 4, ln = lane & 15;
    int m = mt * 64 + w * 16 + ln;
    const _Float16* Qh = Qt + (b * NH_ + h) * L_ * 16;
    const _Float16* Kh = Kt + (b * NH_ + h) * L_ * 16;
    const _Float16* Vp = Vh + (b * NH_ + h) * DK_ * L_;

    half4 kraw = *(const half4*)(Kh + m * 16 + lg * 4);
    half4 kfrag;
    #pragma unroll
    for (int j = 0; j < 4; ++j) kfrag[j] = kraw[j] * (_Float16)0.25f;

    f32x4 accf[4];
    #pragma unroll
    for (int f = 0; f < 4; ++f) accf[f] = (f32x4){0.f, 0.f, 0.f, 0.f};
    float run_sm = 0.f;

    int sv = tid >> 4, sq = tid & 15;             // V staging: row, quad
    const _Float16* vsrc = Vp + sv * L_ + sq * 4;
    half4 vreg = *(const half4*)(vsrc);           // tile 0 prefetch

    for (int lt = 0; lt < 16; ++lt) {
        int cb = lt & 1;
        int l0 = lt * 64;
        *(half4*)(&Vs[cb][sv * VSTR + sq * 4]) = vreg;
        __syncthreads();
        if (lt < 15) vreg = *(const half4*)(vsrc + (lt + 1) * 64);

        f32x4 s[4];
        #pragma unroll
        for (int f = 0; f < 4; ++f) {
            half4 qf = *(const half4*)(Qh + (l0 + f * 16 + ln) * 16 + lg * 4);
            f32x4 z = {0.f, 0.f, 0.f, 0.f};
            s[f] = __builtin_amdgcn_mfma_f32_16x16x16f16(qf, kfrag, z, 0, 0, 0);
        }

        float ts = 0.f;
        half4 pf[4];
        #pragma unroll
        for (int f = 0; f < 4; ++f) {
            float p0 = __expf(s[f][0]);
            float p1 = __expf(s[f][1]);
            float p2 = __expf(s[f][2]);
            float p3 = __expf(s[f][3]);
            ts += (p0 + p1) + (p2 + p3);
            pf[f][0] = (_Float16)p0; pf[f][1] = (_Float16)p1;
            pf[f][2] = (_Float16)p2; pf[f][3] = (_Float16)p3;
        }
        ts += __shfl_xor(ts, 16, 64);
        ts += __shfl_xor(ts, 32, 64);
        run_sm += ts;

        #pragma unroll
        for (int f = 0; f < 4; ++f) {
            half4 vf = *(const half4*)(&Vs[cb][ln * VSTR + f * 16 + lg * 4]);
            accf[f] = __builtin_amdgcn_mfma_f32_16x16x16f16(vf, pf[f], accf[f], 0, 0, 0);
        }
    }

    float inv = 1.f / run_sm;
    #pragma unroll
    for (int r = 0; r < 4; ++r) {
        float a = (accf[0][r] + accf[1][r]) + (accf[2][r] + accf[3][r]);
        Om[(w * 16 + ln) * 16 + lg * 4 + r] = (_Float16)(a * inv);
    }
    __syncthreads();
    if (tid < 128) {
        int ml = tid >> 1, hf = tid & 1;
        half8 hv = *(const half8*)(&Om[ml * 16 + hf * 8]);
        *(half8*)(H16 + (b * L_ + mt * 64 + ml) * 128 + h * 16 + hf * 8) = hv;
    }
}

// ---------- Wo matmul: stage H16 tile to LDS (coalesced), then b-frags from LDS ----------
__global__ __launch_bounds__(256) void k_matmul_h16(
    const float* __restrict__ Wm, const _Float16* __restrict__ H16,
    const float* __restrict__ res, float* __restrict__ out, float* __restrict__ part)
{
    constexpr int HSTR = 136;
    constexpr int CSTR = 36;
    __shared__ _Float16 Xh[32 * HSTR];
    __shared__ float Ct[64 * CSTR];
    __shared__ float red[32];
    int lt = blockIdx.x, rb = blockIdx.y, b = blockIdx.z;
    int tid = threadIdx.x;
    int l0 = lt * 32, r0 = rb * 64;
    const _Float16* Hb = H16 + (size_t)b * L_ * 128;

    {   // stage: thread -> (l = tid>>3, 16-ch segment)
        int l = tid >> 3, seg = tid & 7;
        const _Float16* src = Hb + (l0 + l) * 128 + seg * 16;
        *(half8*)(&Xh[l * HSTR + seg * 16])     = *(const half8*)(src);
        *(half8*)(&Xh[l * HSTR + seg * 16 + 8]) = *(const half8*)(src + 8);
    }
    __syncthreads();

    int w = tid >> 6, lane = tid & 63, lg = lane >> 4, ln = lane & 15;
    int o = r0 + w * 16 + ln;
    const float* wrow = Wm + b * D_ * D_ + o * D_;

    f32x4 acc0 = {0.f, 0.f, 0.f, 0.f};
    f32x4 acc1 = {0.f, 0.f, 0.f, 0.f};
    #pragma unroll
    for (int kk = 0; kk < 8; ++kk) {
        float4 wv = *(const float4*)(wrow + kk * 16 + lg * 4);
        half4 af = {(_Float16)wv.x, (_Float16)wv.y, (_Float16)wv.z, (_Float16)wv.w};
        half4 b0 = *(const half4*)(&Xh[ln * HSTR + kk * 16 + lg * 4]);
        half4 b1 = *(const half4*)(&Xh[(16 + ln) * HSTR + kk * 16 + lg * 4]);
        acc0 = __builtin_amdgcn_mfma_f32_16x16x16f16(af, b0, acc0, 0, 0, 0);
        acc1 = __builtin_amdgcn_mfma_f32_16x16x16f16(af, b1, acc1, 0, 0, 0);
    }

    #pragma unroll
    for (int n = 0; n < 2; ++n) {
        const f32x4& a = n ? acc1 : acc0;
        #pragma unroll
        for (int r = 0; r < 4; ++r)
            Ct[(w * 16 + lg * 4 + r) * CSTR + n * 16 + ln] = a[r];
    }
    __syncthreads();

    float s[2] = {0.f, 0.f};
    {
        int row = tid >> 2, q4 = tid & 3;
        int og = r0 + row, lcol = l0 + q4 * 8;
        int idx = b * BD + og * L_ + lcol;
        float4 c0 = *(const float4*)(&Ct[row * CSTR + q4 * 8]);
        float4 c1 = *(const float4*)(&Ct[row * CSTR + q4 * 8 + 4]);
        float4 r0v = *(const float4*)(res + idx);
        float4 r1v = *(const float4*)(res + idx + 4);
        float cv[8] = {c0.x, c0.y, c0.z, c0.w, c1.x, c1.y, c1.z, c1.w};
        float rv[8] = {r0v.x, r0v.y, r0v.z, r0v.w, r1v.x, r1v.y, r1v.z, r1v.w};
        float ov[8];
        #pragma unroll
        for (int e = 0; e < 8; ++e) {
            float v = cv[e] + rv[e];
            ov[e] = v;
            s[0] += v; s[1] += v * v;
        }
        *(float4*)(out + idx)     = (float4){ov[0], ov[1], ov[2], ov[3]};
        *(float4*)(out + idx + 4) = (float4){ov[4], ov[5], ov[6], ov[7]};
    }
    block_reduce_wave<2>(s, red, part + (b * 64 + rb * 32 + lt) * 8, tid);
}

// ---------- generic MFMA matmul (W[b,o,c]) with LN staging ----------
template<bool RELU, bool ADDRES, bool STATS, bool LNSTAGE>
__global__ __launch_bounds__(256) void k_matmul_mfma(
    const float* __restrict__ Wm, const float* __restrict__ X,
    const float* __restrict__ lnw, const float* __restrict__ lnb,
    const float* __restrict__ pin,
    const float* __restrict__ res, float* __restrict__ out, float* __restrict__ part)
{
    constexpr int XSTR = 136;
    constexpr int CSTR = 36;
    __shared__ _Float16 Xt[32 * XSTR];
    __shared__ float Ct[64 * CSTR];
    __shared__ float stat4[4];
    __shared__ float red[32];
    int lt = blockIdx.x, rb = blockIdx.y, b = blockIdx.z;
    int tid = threadIdx.x;
    int l0 = lt * 32, r0 = rb * 64;

    if constexpr (LNSTAGE) ln_stats_wave0<1>(pin, nullptr, b, stat4, tid);
    float m1 = LNSTAGE ? stat4[0] : 0.f, r1 = LNSTAGE ? stat4[1] : 1.f;
    stage_tile<LNSTAGE, XSTR>(X, lnw, lnb, Xt, b, l0, m1, r1, tid);
    __syncthreads();

    int w = tid >> 6, lane = tid & 63, lg = lane >> 4, ln = lane & 15;
    int o = r0 + w * 16 + ln;
    const float* wrow = Wm + b * D_ * D_ + o * D_;

    f32x4 acc0 = {0.f, 0.f, 0.f, 0.f};
    f32x4 acc1 = {0.f, 0.f, 0.f, 0.f};
    #pragma unroll
    for (int kk = 0; kk < 8; ++kk) {
        float4 wv = *(const float4*)(wrow + kk * 16 + lg * 4);
        half4 af = {(_Float16)wv.x, (_Float16)wv.y, (_Float16)wv.z, (_Float16)wv.w};
        half4 b0 = *(const half4*)(&Xt[ln * XSTR + kk * 16 + lg * 4]);
        half4 b1 = *(const half4*)(&Xt[(16 + ln) * XSTR + kk * 16 + lg * 4]);
        acc0 = __builtin_amdgcn_mfma_f32_16x16x16f16(af, b0, acc0, 0, 0, 0);
        acc1 = __builtin_amdgcn_mfma_f32_16x16x16f16(af, b1, acc1, 0, 0, 0);
    }

    #pragma unroll
    for (int n = 0; n < 2; ++n) {
        const f32x4& a = n ? acc1 : acc0;
        #pragma unroll
        for (int r = 0; r < 4; ++r)
            Ct[(w * 16 + lg * 4 + r) * CSTR + n * 16 + ln] = a[r];
    }
    __syncthreads();

    float s[2] = {0.f, 0.f};
    {
        int row = tid >> 2, q4 = tid & 3;
        int og = r0 + row, lcol = l0 + q4 * 8;
        int idx = b * BD + og * L_ + lcol;
        float4 c0 = *(const float4*)(&Ct[row * CSTR + q4 * 8]);
        float4 c1 = *(const float4*)(&Ct[row * CSTR + q4 * 8 + 4]);
        float cv[8] = {c0.x, c0.y, c0.z, c0.w, c1.x, c1.y, c1.z, c1.w};
        float rv[8] = {0.f, 0.f, 0.f, 0.f, 0.f, 0.f, 0.f, 0.f};
        if constexpr (ADDRES) {
            float4 r0v = *(const float4*)(res + idx);
            float4 r1v = *(const float4*)(res + idx + 4);
            rv[0]=r0v.x; rv[1]=r0v.y; rv[2]=r0v.z; rv[3]=r0v.w;
            rv[4]=r1v.x; rv[5]=r1v.y; rv[6]=r1v.z; rv[7]=r1v.w;
        }
        float ov[8];
        #pragma unroll
        for (int e = 0; e < 8; ++e) {
            float v = cv[e];
            if constexpr (RELU) v = fmaxf(v, 0.f);
            v += rv[e];
            ov[e] = v;
            if constexpr (STATS) { s[0] += v; s[1] += v * v; }
        }
        *(float4*)(out + idx)     = (float4){ov[0], ov[1], ov[2], ov[3]};
        *(float4*)(out + idx + 4) = (float4){ov[4], ov[5], ov[6], ov[7]};
    }
    if constexpr (STATS) block_reduce_wave<2>(s, red, part + (b * 64 + rb * 32 + lt) * 8, tid);
}

// ---------- launch ----------

extern "C" void kernel_launch(void* const* d_in, const int* in_sizes, int n_in,
                              void* d_out, int out_size, void* d_ws, size_t ws_size,
                              hipStream_t stream)
{
    const float* x   = (const float*)d_in[0];
    const float* pos = (const float*)d_in[1];
    const float* lnw = (const float*)d_in[2];
    const float* lnb = (const float*)d_in[3];
    const float* dw  = (const float*)d_in[4];
    const float* pw  = (const float*)d_in[5];
    const float* Wq  = (const float*)d_in[6];
    const float* Wk  = (const float*)d_in[7];
    const float* Wv  = (const float*)d_in[8];
    const float* Wo  = (const float*)d_in[9];
    const float* Wf  = (const float*)d_in[10];
    float* out = (float*)d_out;

    float* ws = (float*)d_ws;
    float* WP = ws;                         // 64*8
    float* P0 = ws + 512;                   // each 8*64*8 = 4096 floats
    float* P1 = P0 + 4096;
    float* P2 = P1 + 4096;
    float* P3 = P2 + 4096;
    float* P4 = P3 + 4096;
    float* P5 = P4 + 4096;
    float* bufA = ws + 32768;
    float* bufB = bufA + (size_t)B_ * BD;
    float* bufC = bufB + (size_t)B_ * BD;   // d (Wo out)
    _Float16* Qt  = (_Float16*)(bufC + (size_t)B_ * BD);
    _Float16* Kt  = Qt + (size_t)B_ * NH_ * L_ * 16;
    _Float16* Vh  = Kt + (size_t)B_ * NH_ * L_ * 16;
    _Float16* H16 = Vh + (size_t)B_ * NH_ * DK_ * L_;

    dim3 cb(64, 8);
    dim3 mb(32, 2, 8);

    k_addpos_wm<<<dim3(64, 9), 256, 0, stream>>>(x, pos, lnw, lnb, bufA, P0, WP);

    k_convblock<1><<<cb, 256, 0, stream>>>(bufA, lnw, lnb, dw + 0*D_*KSZ, pw + 0*D_*D_, WP, P0, bufB, P1);
    k_convblock<2><<<cb, 256, 0, stream>>>(bufB, lnw, lnb, dw + 1*D_*KSZ, pw + 1*D_*D_, WP, P1, bufA, P2);
    k_convblock<2><<<cb, 256, 0, stream>>>(bufA, lnw, lnb, dw + 2*D_*KSZ, pw + 2*D_*D_, WP, P2, bufB, P3);
    k_convblock<2><<<cb, 256, 0, stream>>>(bufB, lnw, lnb, dw + 3*D_*KSZ, pw + 3*D_*D_, WP, P3, bufA, P4);

    k_qkv<<<mb, 256, 0, stream>>>(Wq, Wk, Wv, bufA, lnw, lnb, P4, Qt, Kt, Vh);

    k_attn_mfma<<<dim3(16, NH_, B_), 256, 0, stream>>>(Qt, Kt, Vh, H16);

    k_matmul_h16<<<mb, 256, 0, stream>>>(Wo, H16, bufA, bufC, P5);
    k_matmul_mfma<true, true, false, true><<<mb, 256, 0, stream>>>(Wf, bufC, lnw, lnb, P5, bufC, out, nullptr);
}